// Round 1
// baseline (178.981 us; speedup 1.0000x reference)
//
#include <hip/hip_runtime.h>

#define ROI 31
#define HALF 15
#define H_DIM 256
#define W_DIM 256
#define C_DIM 32

__global__ __launch_bounds__(256) void roi_extract_kernel(
    const float* __restrict__ poses,   // [B,256,256,32]
    const int*   __restrict__ centers, // [N,3] (b,y,x)
    float*       __restrict__ out)     // [N,31,31,32]
{
    const int r = blockIdx.x;          // 0..30  (ROI row)
    const int n = blockIdx.y;          // roi index
    const int t = threadIdx.x;         // 0..255

    // wave-uniform center load (scalar-cached)
    const int b = centers[n * 3 + 0];
    const int y = centers[n * 3 + 1];
    const int x = centers[n * 3 + 2];

    const int rr   = y + r - HALF;
    const bool rok = (rr >= 0) && (rr < H_DIM);
    const int rrc  = min(max(rr, 0), H_DIM - 1);

    if (t >= ROI * (C_DIM / 4)) return;   // 248 active threads
    const int c = t >> 3;                 // ROI col 0..30
    const int q = t & 7;                  // float4 index within pixel (32 ch = 8 x float4)

    const int cc   = x + c - HALF;
    const bool cok = (cc >= 0) && (cc < W_DIM);
    const int ccc  = min(max(cc, 0), W_DIM - 1);

    float4 v = make_float4(0.f, 0.f, 0.f, 0.f);
    if (rok && cok) {
        const float4* src = reinterpret_cast<const float4*>(
            poses + (((size_t)b * H_DIM + rrc) * W_DIM + ccc) * C_DIM);
        v = src[q];
    }
    float4* dst = reinterpret_cast<float4*>(
        out + (((size_t)n * ROI + r) * ROI + c) * C_DIM);
    dst[q] = v;
}

extern "C" void kernel_launch(void* const* d_in, const int* in_sizes, int n_in,
                              void* d_out, int out_size, void* d_ws, size_t ws_size,
                              hipStream_t stream) {
    const float* poses   = (const float*)d_in[0];
    const int*   centers = (const int*)d_in[1];
    float*       out     = (float*)d_out;

    const int N = in_sizes[1] / 3;   // number of ROIs

    dim3 grid(ROI, N);
    dim3 block(256);
    roi_extract_kernel<<<grid, block, 0, stream>>>(poses, centers, out);
}

// Round 2
// 144.854 us; speedup vs baseline: 1.2356x; 1.2356x over previous
//
#include <hip/hip_runtime.h>

#define ROI 31
#define HALF 15
#define H_DIM 256
#define W_DIM 256
#define C_DIM 32

typedef float vfloat4 __attribute__((ext_vector_type(4)));

__global__ __launch_bounds__(256) void roi_extract_kernel(
    const float* __restrict__ poses,   // [B,256,256,32]
    const int*   __restrict__ centers, // [N,3] (b,y,x)
    float*       __restrict__ out)     // [N,31,31,32]
{
    const int n = blockIdx.x;          // ROI index
    const int t = threadIdx.x;         // 0..255

    // wave-uniform center load (b = blockIdx-based -> scalar loads)
    const int b = centers[n * 3 + 0];
    const int y = centers[n * 3 + 1];
    const int x = centers[n * 3 + 2];

    if (t >= ROI * (C_DIM / 4)) return;   // 248 active threads
    const int c = t >> 3;                 // ROI col 0..30
    const int q = t & 7;                  // float4 index within pixel

    const int cc   = x + c - HALF;
    const bool cok = (cc >= 0) && (cc < W_DIM);
    const int ccc  = min(max(cc, 0), W_DIM - 1);

    // per-thread bases
    const vfloat4* src = reinterpret_cast<const vfloat4*>(
        poses + ((size_t)b * H_DIM * W_DIM + ccc) * C_DIM) + q;
    vfloat4* dst = reinterpret_cast<vfloat4*>(
        out + ((size_t)n * ROI * ROI + c) * C_DIM) + q;

    const int r0 = y - HALF;                       // source row of ROI row 0
    const size_t src_row_stride = (size_t)W_DIM * (C_DIM / 4);  // float4 units
    const size_t dst_row_stride = (size_t)ROI * (C_DIM / 4);

    #pragma unroll
    for (int r = 0; r < ROI; ++r) {
        const int rr = r0 + r;
        const bool ok = cok && (rr >= 0) && (rr < H_DIM);
        vfloat4 v = (vfloat4)0.0f;
        if (ok) {
            v = src[(size_t)rr * src_row_stride];
        }
        // stream the output past the caches; keep L3 for the input
        __builtin_nontemporal_store(v, dst + (size_t)r * dst_row_stride);
    }
}

extern "C" void kernel_launch(void* const* d_in, const int* in_sizes, int n_in,
                              void* d_out, int out_size, void* d_ws, size_t ws_size,
                              hipStream_t stream) {
    const float* poses   = (const float*)d_in[0];
    const int*   centers = (const int*)d_in[1];
    float*       out     = (float*)d_out;

    const int N = in_sizes[1] / 3;   // number of ROIs

    roi_extract_kernel<<<dim3(N), dim3(256), 0, stream>>>(poses, centers, out);
}